// Round 8
// baseline (879.421 us; speedup 1.0000x reference)
//
#include <hip/hip_runtime.h>
#include <hip/hip_bf16.h>

#define NNODES 50000
#define NEDGES 800000
#define NHEAD 8
#define CAP 96                       // edge slots per partition window
#define NBLK ((NEDGES + CAP - 1) / CAP)
#define MAXSPAN 384                  // max edges a block can own (>= CAP + max node degree)

typedef __attribute__((ext_vector_type(8))) short short8v;
typedef __attribute__((ext_vector_type(4))) float f32x4;

union U8 { short8v v; unsigned short u[8]; };

__device__ inline unsigned short f2bf(float f) {
    unsigned int u = __float_as_uint(f);
    unsigned int r = (u + 0x7FFFu + ((u >> 16) & 1u)) >> 16;
    return (unsigned short)r;
}
__device__ inline float bf2f(unsigned int u) {
    return __uint_as_float(u << 16);
}

// ---- prep: W[k][n] f32 -> Wt[n][k] bf16, for WQ,WK,WV,WE1 ----
__global__ void prep_weights(const float* __restrict__ WQ, const float* __restrict__ WK,
                             const float* __restrict__ WV, const float* __restrict__ WE1,
                             unsigned short* __restrict__ Wt) {
    int idx = blockIdx.x * 256 + threadIdx.x;
    if (idx >= 4 * 16384) return;
    int m = idx >> 14, r = idx & 16383;
    int k = r >> 7, n = r & 127;
    const float* W = (m == 0) ? WQ : (m == 1) ? WK : (m == 2) ? WV : WE1;
    Wt[m * 16384 + n * 128 + k] = f2bf(W[k * 128 + n]);
}

// swizzled LDS byte offset: row-major [rows][128 bf16] (256B rows), 16-slot XOR swizzle
__device__ inline int swz(int row, int byteInRow) {
    return row * 256 + (byteInRow ^ ((row & 15) << 4));
}

// stage one 128x128 bf16 (pre-transposed) weight into swizzled LDS, 256 threads
__device__ inline void stageW256(char* Wl, const unsigned short* __restrict__ Wtm, int t) {
    int row = t >> 1, half = t & 1;
    const unsigned short* src = Wtm + row * 128 + half * 64;
#pragma unroll
    for (int i = 0; i < 8; i++) {
        short8v v = *reinterpret_cast<const short8v*>(src + i * 8);
        *reinterpret_cast<short8v*>(Wl + swz(row, half * 128 + i * 16)) = v;
    }
}

// stage one 128x128 bf16 (pre-transposed) weight into swizzled LDS, 512 threads
__device__ inline void stageW512(char* Wl, const unsigned short* __restrict__ Wtm, int t) {
    int row = t >> 2, q = t & 3;
    const unsigned short* src = Wtm + row * 128 + q * 32;
#pragma unroll
    for (int i = 0; i < 4; i++) {
        short8v v = *reinterpret_cast<const short8v*>(src + i * 8);
        *reinterpret_cast<short8v*>(Wl + swz(row, q * 64 + i * 16)) = v;
    }
}

// load one bf16 fragment set (4 k-steps) for global row `aptr`, lane k-group lg
__device__ inline void loadAfrag(const float* aptr, int lg, short8v* a, bool ok) {
#pragma unroll
    for (int kk = 0; kk < 4; kk++) {
        U8 h;
        if (ok) {
            float4 f0 = *reinterpret_cast<const float4*>(aptr + kk * 32 + lg * 8);
            float4 f1 = *reinterpret_cast<const float4*>(aptr + kk * 32 + lg * 8 + 4);
            h.u[0] = f2bf(f0.x); h.u[1] = f2bf(f0.y); h.u[2] = f2bf(f0.z); h.u[3] = f2bf(f0.w);
            h.u[4] = f2bf(f1.x); h.u[5] = f2bf(f1.y); h.u[6] = f2bf(f1.z); h.u[7] = f2bf(f1.w);
        } else {
#pragma unroll
            for (int j = 0; j < 8; j++) h.u[j] = 0;
        }
        a[kk] = h.v;
    }
}

// ---- proj: Q = x@WQ + bQ ; K = x@WK ; V = x@WV ----
__global__ __launch_bounds__(256, 4) void proj_qkv(const float* __restrict__ x,
                                                   const unsigned short* __restrict__ Wt,
                                                   const float* __restrict__ bQ,
                                                   float* __restrict__ Q, float* __restrict__ K,
                                                   float* __restrict__ V) {
    __shared__ __align__(16) char Wl[32768];
    int t = threadIdx.x;
    int nb = blockIdx.x * 64;
    int lane = t & 63, w = t >> 6;
    int lg = lane >> 4, lr = lane & 15;

    int arow = nb + w * 16 + lr;
    bool ok = arow < NNODES;
    short8v a[4];
    loadAfrag(x + (size_t)arow * 128, lg, a, ok);

    float bq[8];
#pragma unroll
    for (int n = 0; n < 8; n++) bq[n] = bQ[n * 16 + lr];

    for (int m = 0; m < 3; m++) {
        __syncthreads();
        stageW256(Wl, Wt + m * 16384, t);
        __syncthreads();

        f32x4 acc[8];
#pragma unroll
        for (int n = 0; n < 8; n++) acc[n] = (f32x4){0.f, 0.f, 0.f, 0.f};
#pragma unroll
        for (int kk = 0; kk < 4; kk++) {
#pragma unroll
            for (int n = 0; n < 8; n++) {
                short8v b = *reinterpret_cast<short8v*>(Wl + swz(n * 16 + lr, (kk * 32 + lg * 8) * 2));
                acc[n] = __builtin_amdgcn_mfma_f32_16x16x32_bf16(a[kk], b, acc[n], 0, 0, 0);
            }
        }
        float* out = (m == 0) ? Q : (m == 1) ? K : V;
#pragma unroll
        for (int n = 0; n < 8; n++) {
            int c = n * 16 + lr;
            float bias = (m == 0) ? bq[n] : 0.f;
#pragma unroll
            for (int r = 0; r < 4; r++) {
                int gr = nb + w * 16 + lg * 4 + r;
                if (gr < NNODES) out[(size_t)gr * 128 + c] = acc[n][r] + bias;
            }
        }
    }
}

// ---- counting sort by dst ----
__global__ void hist_kernel(const int* __restrict__ eidx, int* __restrict__ histo) {
    int e = blockIdx.x * 256 + threadIdx.x;
    if (e >= NEDGES) return;
    atomicAdd(&histo[eidx[NEDGES + e]], 1);
}

__global__ __launch_bounds__(256) void scanA(const int* __restrict__ histo, int* __restrict__ bsum) {
    __shared__ int l[4];
    int t = threadIdx.x;
    int idx = blockIdx.x * 256 + t;
    int v = (idx < NNODES) ? histo[idx] : 0;
#pragma unroll
    for (int off = 32; off; off >>= 1) v += __shfl_down(v, off);
    if ((t & 63) == 0) l[t >> 6] = v;
    __syncthreads();
    if (t == 0) bsum[blockIdx.x] = l[0] + l[1] + l[2] + l[3];
}

__global__ __launch_bounds__(256) void scanB(const int* __restrict__ bsum, int* __restrict__ boff) {
    __shared__ int l[256];
    int t = threadIdx.x;
    int v = (t < 196) ? bsum[t] : 0;
    l[t] = v;
    __syncthreads();
    for (int off = 1; off < 256; off <<= 1) {
        int tmp = (t >= off) ? l[t - off] : 0;
        __syncthreads();
        l[t] += tmp;
        __syncthreads();
    }
    if (t < 196) boff[t] = l[t] - v;
}

__global__ __launch_bounds__(256) void scanC(const int* __restrict__ histo,
                                             const int* __restrict__ boff,
                                             int* __restrict__ start, int* __restrict__ cursor) {
    __shared__ int l[256];
    int t = threadIdx.x;
    int idx = blockIdx.x * 256 + t;
    int v = (idx < NNODES) ? histo[idx] : 0;
    l[t] = v;
    __syncthreads();
    for (int off = 1; off < 256; off <<= 1) {
        int tmp = (t >= off) ? l[t - off] : 0;
        __syncthreads();
        l[t] += tmp;
        __syncthreads();
    }
    int excl = l[t] - v + boff[blockIdx.x];
    if (idx <= NNODES) {
        start[idx] = excl;
        if (idx < NNODES) cursor[idx] = excl;
    }
}

__global__ void scatter_edges(const int* __restrict__ eidx, int* __restrict__ cursor,
                              int* __restrict__ sortedE) {
    int e = blockIdx.x * 256 + threadIdx.x;
    if (e >= NEDGES) return;
    int d = eidx[NEDGES + e];
    int pos = atomicAdd(&cursor[d], 1);
    sortedE[pos] = e;
}

// ---- partition: firstNode[b] = lower_bound(start[], b*CAP) ----
__global__ void partition_blocks(const int* __restrict__ start, int* __restrict__ firstNode) {
    int b = blockIdx.x * 256 + threadIdx.x;
    if (b > NBLK) return;
    int target = b * CAP;
    int lo = 0, hi = NNODES;
    while (lo < hi) {
        int mid = (lo + hi) >> 1;
        if (start[mid] < target) lo = mid + 1; else hi = mid;
    }
    firstNode[b] = lo;
}

// ---- mega: E GEMM + score + wE + in-LDS softmax + aggregation, dst-sorted ----
// Block owns whole nodes [n0,n1) = [firstNode[b], firstNode[b+1]), span <= MAXSPAN edges.
__global__ __launch_bounds__(512, 6) void edge_mega(const float* __restrict__ EA,
                                                    const unsigned short* __restrict__ Wt,
                                                    const float* __restrict__ bE1,
                                                    const int* __restrict__ eidx,
                                                    const float* __restrict__ Q,
                                                    const float* __restrict__ K,
                                                    const float* __restrict__ V,
                                                    const int* __restrict__ sortedE,
                                                    const int* __restrict__ start,
                                                    const int* __restrict__ firstNode,
                                                    float* __restrict__ wE,
                                                    float* __restrict__ wV) {
    __shared__ __align__(16) char Wl[32768];   // weights, reused as E tile per tile
    __shared__ float exL[MAXSPAN][8];
    __shared__ int eG[MAXSPAN], sG[MAXSPAN], dG[MAXSPAN];

    int b = blockIdx.x;
    int n0 = firstNode[b], n1 = firstNode[b + 1];
    if (n0 >= n1) return;
    int gbase = start[n0];
    int span = start[n1] - gbase;
    if (span > MAXSPAN) span = MAXSPAN;  // safety (unreachable for this data)

    int t = threadIdx.x;
    int lane = t & 63, w = t >> 6;
    int lg = lane >> 4, lr = lane & 15;

    for (int i = t; i < span; i += 512) {
        int e = sortedE[gbase + i];
        eG[i] = e;
        sG[i] = eidx[e];
        dG[i] = eidx[NEDGES + e];
    }
    __syncthreads();

    float be[8];
#pragma unroll
    for (int n = 0; n < 8; n++) be[n] = bE1[n * 16 + lr];

    // -------- phase 1: tiles of 128 edges: GEMM -> E LDS -> score epilogue --------
    for (int base = 0; base < span; base += 128) {
        stageW512(Wl, Wt + 3 * 16384, t);

        int slot = base + w * 16 + lr;
        bool act = slot < span;
        short8v a[4];
        loadAfrag(EA + (size_t)(act ? eG[slot] : 0) * 128, lg, a, act);

        __syncthreads();  // weights staged

        f32x4 acc[8];
#pragma unroll
        for (int n = 0; n < 8; n++) acc[n] = (f32x4){0.f, 0.f, 0.f, 0.f};
#pragma unroll
        for (int kk = 0; kk < 4; kk++) {
#pragma unroll
            for (int n = 0; n < 8; n++) {
                short8v bfr = *reinterpret_cast<short8v*>(Wl + swz(n * 16 + lr, (kk * 32 + lg * 8) * 2));
                acc[n] = __builtin_amdgcn_mfma_f32_16x16x32_bf16(a[kk], bfr, acc[n], 0, 0, 0);
            }
        }
        __syncthreads();  // weights consumed; Wl now reusable

        // write E = acc + bias to LDS bf16; wave w owns rows [w*16, w*16+16)
#pragma unroll
        for (int n = 0; n < 8; n++) {
#pragma unroll
            for (int r = 0; r < 4; r++) {
                int row = w * 16 + lg * 4 + r;
                *reinterpret_cast<unsigned short*>(Wl + swz(row, (n * 16 + lr) * 2)) =
                    f2bf(acc[n][r] + be[n]);
            }
        }
        // epilogue: 64 lanes span one edge row (2 cols/lane)
        int h = lane >> 3;
#pragma unroll 4
        for (int i = 0; i < 16; i++) {
            int loc = w * 16 + i;
            int slot2 = base + loc;
            if (slot2 >= span) break;   // wave-uniform
            int e = eG[slot2], s = sG[slot2], d = dG[slot2];
            unsigned int ep = *reinterpret_cast<unsigned int*>(Wl + swz(loc, lane * 4));
            float e0 = bf2f(ep & 0xffffu);
            float e1 = bf2f(ep >> 16);
            float2 kv = *reinterpret_cast<const float2*>(K + (size_t)s * 128 + lane * 2);
            float2 qv = *reinterpret_cast<const float2*>(Q + (size_t)d * 128 + lane * 2);
            float s0 = e0 * kv.x * qv.x;
            float s1 = e1 * kv.y * qv.y;
            *reinterpret_cast<float2*>(wE + (size_t)e * 128 + lane * 2) = make_float2(s0, s1);
            float sum = s0 + s1;
            sum += __shfl_xor(sum, 1);
            sum += __shfl_xor(sum, 2);
            sum += __shfl_xor(sum, 4);
            if ((lane & 7) == 0) {
                float sh = fminf(fmaxf(sum * 0.25f, -5.f), 5.f);
                exL[slot2][h] = __expf(sh);   // |score|<=5 -> no segment max needed
            }
        }
        __syncthreads();  // epilogue E reads done before next tile overwrites Wl
    }

    // -------- phase 2/3: wave per node: denom reduce + weighted aggregation --------
    int half = lane >> 5, li = lane & 31;
    int col = li * 4, h2 = li >> 2;
    int hh = lane >> 3, j = lane & 7;
    for (int n = n0 + w; n < n1; n += 8) {
        int sl0 = start[n] - gbase, sl1 = start[n + 1] - gbase;
        float den = 0.f;
        for (int ss = sl0 + j; ss < sl1; ss += 8) den += exL[ss][hh];
        den += __shfl_xor(den, 1);
        den += __shfl_xor(den, 2);
        den += __shfl_xor(den, 4);
        float inv = 1.f / (den + 1e-16f);
        float alinv = __shfl(inv, h2 * 8);   // inv for this lane's head
        float4 ac = make_float4(0.f, 0.f, 0.f, 0.f);
        for (int ss = sl0 + half; ss < sl1; ss += 2) {
            int e2 = eG[ss], s2 = sG[ss];
            float al = exL[ss][h2] * alinv;
            float4 we = *reinterpret_cast<const float4*>(wE + (size_t)e2 * 128 + col);  // L2-hot
            float4 vv = *reinterpret_cast<const float4*>(V + (size_t)s2 * 128 + col);
            ac.x += (vv.x + we.x) * al;
            ac.y += (vv.y + we.y) * al;
            ac.z += (vv.z + we.z) * al;
            ac.w += (vv.w + we.w) * al;
        }
        ac.x += __shfl_xor(ac.x, 32);
        ac.y += __shfl_xor(ac.y, 32);
        ac.z += __shfl_xor(ac.z, 32);
        ac.w += __shfl_xor(ac.w, 32);
        if (half == 0) *reinterpret_cast<float4*>(wV + (size_t)n * 128 + col) = ac;
    }
}

extern "C" void kernel_launch(void* const* d_in, const int* in_sizes, int n_in,
                              void* d_out, int out_size, void* d_ws, size_t ws_size,
                              hipStream_t stream) {
    const float* x    = (const float*)d_in[0];
    const float* ea   = (const float*)d_in[1];
    const int*   eidx = (const int*)d_in[2];
    const float* WQ   = (const float*)d_in[3];
    const float* bQ   = (const float*)d_in[4];
    const float* WK   = (const float*)d_in[5];
    const float* WV   = (const float*)d_in[6];
    const float* WE1  = (const float*)d_in[7];
    const float* bE1  = (const float*)d_in[8];

    float* wV = (float*)d_out;                           // [50000,128]
    float* wE = (float*)d_out + (size_t)NNODES * 128;    // [800000,128]

    float* Q      = (float*)d_ws;
    float* K      = Q + (size_t)NNODES * 128;
    float* V      = K + (size_t)NNODES * 128;
    unsigned short* Wt = (unsigned short*)(V + (size_t)NNODES * 128); // 4x[128][128] bf16
    int* histo     = (int*)(Wt + 4 * 16384);             // 50176
    int* start     = histo + 50176;                      // 50177
    int* cursor    = start + 50177;                      // 50176
    int* sortedE   = cursor + 50176;                     // 800000
    int* bsum      = sortedE + NEDGES;                   // 256
    int* boff      = bsum + 256;                         // 256
    int* firstNode = boff + 256;                         // NBLK+1

    hipMemsetAsync(histo, 0, (size_t)50176 * 4, stream);

    prep_weights<<<(4 * 16384 + 255) / 256, 256, 0, stream>>>(WQ, WK, WV, WE1, Wt);
    hist_kernel<<<(NEDGES + 255) / 256, 256, 0, stream>>>(eidx, histo);
    scanA<<<196, 256, 0, stream>>>(histo, bsum);
    scanB<<<1, 256, 0, stream>>>(bsum, boff);
    scanC<<<196, 256, 0, stream>>>(histo, boff, start, cursor);
    scatter_edges<<<(NEDGES + 255) / 256, 256, 0, stream>>>(eidx, cursor, sortedE);
    partition_blocks<<<(NBLK + 256) / 256, 256, 0, stream>>>(start, firstNode);
    proj_qkv<<<(NNODES + 63) / 64, 256, 0, stream>>>(x, Wt, bQ, Q, K, V);
    edge_mega<<<NBLK, 512, 0, stream>>>(ea, Wt, bE1, eidx, Q, K, V, sortedE, start,
                                        firstNode, wE, wV);
}

// Round 9
// 572.249 us; speedup vs baseline: 1.5368x; 1.5368x over previous
//
#include <hip/hip_runtime.h>
#include <hip/hip_bf16.h>

#define NNODES 50000
#define NEDGES 800000
#define NHEAD 8

typedef __attribute__((ext_vector_type(8))) short short8v;
typedef __attribute__((ext_vector_type(4))) float f32x4;

union U8 { short8v v; unsigned short u[8]; };

__device__ inline unsigned short f2bf(float f) {
    unsigned int u = __float_as_uint(f);
    unsigned int r = (u + 0x7FFFu + ((u >> 16) & 1u)) >> 16;
    return (unsigned short)r;
}
__device__ inline float bf2f(unsigned int u) {
    return __uint_as_float(u << 16);
}

// ---- prep: W[k][n] f32 -> Wt[n][k] bf16, for WQ,WK,WV,WE1 ----
__global__ void prep_weights(const float* __restrict__ WQ, const float* __restrict__ WK,
                             const float* __restrict__ WV, const float* __restrict__ WE1,
                             unsigned short* __restrict__ Wt) {
    int idx = blockIdx.x * 256 + threadIdx.x;
    if (idx >= 4 * 16384) return;
    int m = idx >> 14, r = idx & 16383;
    int k = r >> 7, n = r & 127;
    const float* W = (m == 0) ? WQ : (m == 1) ? WK : (m == 2) ? WV : WE1;
    Wt[m * 16384 + n * 128 + k] = f2bf(W[k * 128 + n]);
}

// swizzled LDS byte offset: row-major [rows][128 bf16] (256B rows), 16-slot XOR swizzle
__device__ inline int swz(int row, int byteInRow) {
    return row * 256 + (byteInRow ^ ((row & 15) << 4));
}

// stage one 128x128 bf16 (pre-transposed) weight into swizzled LDS, 256 threads
__device__ inline void stageW256(char* Wl, const unsigned short* __restrict__ Wtm, int t) {
    int row = t >> 1, half = t & 1;
    const unsigned short* src = Wtm + row * 128 + half * 64;
#pragma unroll
    for (int i = 0; i < 8; i++) {
        short8v v = *reinterpret_cast<const short8v*>(src + i * 8);
        *reinterpret_cast<short8v*>(Wl + swz(row, half * 128 + i * 16)) = v;
    }
}

// stage one 128x128 bf16 (pre-transposed) weight into swizzled LDS, 512 threads
__device__ inline void stageW512(char* Wl, const unsigned short* __restrict__ Wtm, int t) {
    int row = t >> 2, q = t & 3;
    const unsigned short* src = Wtm + row * 128 + q * 32;
#pragma unroll
    for (int i = 0; i < 4; i++) {
        short8v v = *reinterpret_cast<const short8v*>(src + i * 8);
        *reinterpret_cast<short8v*>(Wl + swz(row, q * 64 + i * 16)) = v;
    }
}

// load one bf16 fragment set (4 k-steps) for global row `aptr`, lane k-group lg
__device__ inline void loadAfrag(const float* aptr, int lg, short8v* a, bool ok) {
#pragma unroll
    for (int kk = 0; kk < 4; kk++) {
        U8 h;
        if (ok) {
            float4 f0 = *reinterpret_cast<const float4*>(aptr + kk * 32 + lg * 8);
            float4 f1 = *reinterpret_cast<const float4*>(aptr + kk * 32 + lg * 8 + 4);
            h.u[0] = f2bf(f0.x); h.u[1] = f2bf(f0.y); h.u[2] = f2bf(f0.z); h.u[3] = f2bf(f0.w);
            h.u[4] = f2bf(f1.x); h.u[5] = f2bf(f1.y); h.u[6] = f2bf(f1.z); h.u[7] = f2bf(f1.w);
        } else {
#pragma unroll
            for (int j = 0; j < 8; j++) h.u[j] = 0;
        }
        a[kk] = h.v;
    }
}

// ---- proj: Q = x@WQ + bQ ; K = x@WK ; V = x@WV ----
__global__ __launch_bounds__(256, 4) void proj_qkv(const float* __restrict__ x,
                                                   const unsigned short* __restrict__ Wt,
                                                   const float* __restrict__ bQ,
                                                   float* __restrict__ Q, float* __restrict__ K,
                                                   float* __restrict__ V) {
    __shared__ __align__(16) char Wl[32768];
    int t = threadIdx.x;
    int nb = blockIdx.x * 64;
    int lane = t & 63, w = t >> 6;
    int lg = lane >> 4, lr = lane & 15;

    int arow = nb + w * 16 + lr;
    bool ok = arow < NNODES;
    short8v a[4];
    loadAfrag(x + (size_t)arow * 128, lg, a, ok);

    float bq[8];
#pragma unroll
    for (int n = 0; n < 8; n++) bq[n] = bQ[n * 16 + lr];

    for (int m = 0; m < 3; m++) {
        __syncthreads();
        stageW256(Wl, Wt + m * 16384, t);
        __syncthreads();

        f32x4 acc[8];
#pragma unroll
        for (int n = 0; n < 8; n++) acc[n] = (f32x4){0.f, 0.f, 0.f, 0.f};
#pragma unroll
        for (int kk = 0; kk < 4; kk++) {
#pragma unroll
            for (int n = 0; n < 8; n++) {
                short8v b = *reinterpret_cast<short8v*>(Wl + swz(n * 16 + lr, (kk * 32 + lg * 8) * 2));
                acc[n] = __builtin_amdgcn_mfma_f32_16x16x32_bf16(a[kk], b, acc[n], 0, 0, 0);
            }
        }
        float* out = (m == 0) ? Q : (m == 1) ? K : V;
#pragma unroll
        for (int n = 0; n < 8; n++) {
            int c = n * 16 + lr;
            float bias = (m == 0) ? bq[n] : 0.f;
#pragma unroll
            for (int r = 0; r < 4; r++) {
                int gr = nb + w * 16 + lg * 4 + r;
                if (gr < NNODES) out[(size_t)gr * 128 + c] = acc[n][r] + bias;
            }
        }
    }
}

// ---- edge pass: E GEMM -> E-tile in LDS (bf16) -> row-parallel gather epilogue ----
// 512 threads = 8 waves, 128 edges/block, streaming edge order (coalesced EA/wE).
// scoreH stores ex=exp(clamp(sum/4)) (|score|<=5 -> no segment max); denom atomic (L2).
__global__ __launch_bounds__(512, 8) void edge_score(const float* __restrict__ EA,
                                                     const unsigned short* __restrict__ Wt,
                                                     const float* __restrict__ bE1,
                                                     const int* __restrict__ eidx,
                                                     const float* __restrict__ Q,
                                                     const float* __restrict__ K,
                                                     float* __restrict__ wE,
                                                     float* __restrict__ scoreH,
                                                     float* __restrict__ denom) {
    __shared__ __align__(16) char Wl[32768];   // weights, then E tile (128x128 bf16)
    __shared__ int srcL[128], dstL[128];
    int t = threadIdx.x;
    int eb = blockIdx.x * 128;
    int lane = t & 63, w = t >> 6;
    int lg = lane >> 4, lr = lane & 15;

    int arow = eb + w * 16 + lr;  // always < NEDGES (grid exact)
    short8v a[4];
    loadAfrag(EA + (size_t)arow * 128, lg, a, true);

    stageW512(Wl, Wt + 3 * 16384, t);
    if (t < 128) srcL[t] = eidx[eb + t];
    else if (t < 256) dstL[t - 128] = eidx[NEDGES + eb + t - 128];
    float be[8];
#pragma unroll
    for (int n = 0; n < 8; n++) be[n] = bE1[n * 16 + lr];

    __syncthreads();

    f32x4 acc[8];
#pragma unroll
    for (int n = 0; n < 8; n++) acc[n] = (f32x4){0.f, 0.f, 0.f, 0.f};
#pragma unroll
    for (int kk = 0; kk < 4; kk++) {
#pragma unroll
        for (int n = 0; n < 8; n++) {
            short8v b = *reinterpret_cast<short8v*>(Wl + swz(n * 16 + lr, (kk * 32 + lg * 8) * 2));
            acc[n] = __builtin_amdgcn_mfma_f32_16x16x32_bf16(a[kk], b, acc[n], 0, 0, 0);
        }
    }

    __syncthreads();  // all waves done reading the weight tile

    // write E = acc + bias to LDS as bf16; wave w owns rows [w*16, w*16+16)
#pragma unroll
    for (int n = 0; n < 8; n++) {
#pragma unroll
        for (int r = 0; r < 4; r++) {
            int row = w * 16 + lg * 4 + r;
            *reinterpret_cast<unsigned short*>(Wl + swz(row, (n * 16 + lr) * 2)) =
                f2bf(acc[n][r] + be[n]);
        }
    }
    // no barrier: each wave reads back only its own rows

    // gather epilogue: 64 lanes span one edge row (2 cols/lane)
    int h = lane >> 3;  // head of this lane's columns
#pragma unroll 8
    for (int i = 0; i < 16; i++) {
        int loc = w * 16 + i;
        int e = eb + loc;
        int s = srcL[loc], d = dstL[loc];
        unsigned int ep = *reinterpret_cast<unsigned int*>(Wl + swz(loc, lane * 4));
        float e0 = bf2f(ep & 0xffffu);
        float e1 = bf2f(ep >> 16);
        float2 kv = *reinterpret_cast<const float2*>(K + (size_t)s * 128 + lane * 2);
        float2 qv = *reinterpret_cast<const float2*>(Q + (size_t)d * 128 + lane * 2);
        float s0 = e0 * kv.x * qv.x;
        float s1 = e1 * kv.y * qv.y;
        *reinterpret_cast<float2*>(wE + (size_t)e * 128 + lane * 2) = make_float2(s0, s1);
        float sum = s0 + s1;
        sum += __shfl_xor(sum, 1);
        sum += __shfl_xor(sum, 2);
        sum += __shfl_xor(sum, 4);
        if ((lane & 7) == 0) {
            float sh = fminf(fmaxf(sum * 0.25f, -5.f), 5.f);
            float ex = __expf(sh);
            scoreH[(size_t)e * 8 + h] = ex;
            unsafeAtomicAdd(&denom[d * 8 + h], ex);
        }
    }
}

// ---- counting sort by dst ----
__global__ void hist_kernel(const int* __restrict__ eidx, int* __restrict__ histo) {
    int e = blockIdx.x * 256 + threadIdx.x;
    if (e >= NEDGES) return;
    atomicAdd(&histo[eidx[NEDGES + e]], 1);
}

__global__ __launch_bounds__(256) void scanA(const int* __restrict__ histo, int* __restrict__ bsum) {
    __shared__ int l[4];
    int t = threadIdx.x;
    int idx = blockIdx.x * 256 + t;
    int v = (idx < NNODES) ? histo[idx] : 0;
#pragma unroll
    for (int off = 32; off; off >>= 1) v += __shfl_down(v, off);
    if ((t & 63) == 0) l[t >> 6] = v;
    __syncthreads();
    if (t == 0) bsum[blockIdx.x] = l[0] + l[1] + l[2] + l[3];
}

__global__ __launch_bounds__(256) void scanB(const int* __restrict__ bsum, int* __restrict__ boff) {
    __shared__ int l[256];
    int t = threadIdx.x;
    int v = (t < 196) ? bsum[t] : 0;
    l[t] = v;
    __syncthreads();
    for (int off = 1; off < 256; off <<= 1) {
        int tmp = (t >= off) ? l[t - off] : 0;
        __syncthreads();
        l[t] += tmp;
        __syncthreads();
    }
    if (t < 196) boff[t] = l[t] - v;
}

__global__ __launch_bounds__(256) void scanC(const int* __restrict__ histo,
                                             const int* __restrict__ boff,
                                             int* __restrict__ start, int* __restrict__ cursor) {
    __shared__ int l[256];
    int t = threadIdx.x;
    int idx = blockIdx.x * 256 + t;
    int v = (idx < NNODES) ? histo[idx] : 0;
    l[t] = v;
    __syncthreads();
    for (int off = 1; off < 256; off <<= 1) {
        int tmp = (t >= off) ? l[t - off] : 0;
        __syncthreads();
        l[t] += tmp;
        __syncthreads();
    }
    int excl = l[t] - v + boff[blockIdx.x];
    if (idx <= NNODES) {
        start[idx] = excl;
        if (idx < NNODES) cursor[idx] = excl;
    }
}

// scatter edges sorted by dst; also emit src per sorted slot (kills eidx gather later)
__global__ void scatter_edges(const int* __restrict__ eidx, int* __restrict__ cursor,
                              int* __restrict__ sortedE, int* __restrict__ sortedS) {
    int e = blockIdx.x * 256 + threadIdx.x;
    if (e >= NEDGES) return;
    int d = eidx[NEDGES + e];
    int s = eidx[e];
    int pos = atomicAdd(&cursor[d], 1);
    sortedE[pos] = e;
    sortedS[pos] = s;
}

// ---- aggregation: one wave per dst node; alpha = ex * 1/denom; single pass ----
// 2 edges per iteration: half-waves cover edges 2i / 2i+1, float4 columns.
__global__ __launch_bounds__(256, 8) void aggregate_pernode(const int* __restrict__ sortedE,
                                                            const int* __restrict__ sortedS,
                                                            const int* __restrict__ start,
                                                            const float* __restrict__ scoreH,
                                                            const float* __restrict__ denom,
                                                            const float* __restrict__ V,
                                                            const float* __restrict__ wE,
                                                            float* __restrict__ wV) {
    __shared__ int eL[4][64];
    __shared__ int sL[4][64];
    __shared__ float aL[4][512];
    int w = threadIdx.x >> 6;
    int n = blockIdx.x * 4 + w;
    if (n >= NNODES) return;
    int lane = threadIdx.x & 63;
    int half = lane >> 5, li = lane & 31;
    int col = li * 4, h = li >> 2;
    int s0 = start[n], cnt = start[n + 1] - s0;

    float4 d0 = *reinterpret_cast<const float4*>(denom + n * 8);
    float4 d1 = *reinterpret_cast<const float4*>(denom + n * 8 + 4);
    float inv[8];
    inv[0] = 1.f / (d0.x + 1e-16f); inv[1] = 1.f / (d0.y + 1e-16f);
    inv[2] = 1.f / (d0.z + 1e-16f); inv[3] = 1.f / (d0.w + 1e-16f);
    inv[4] = 1.f / (d1.x + 1e-16f); inv[5] = 1.f / (d1.y + 1e-16f);
    inv[6] = 1.f / (d1.z + 1e-16f); inv[7] = 1.f / (d1.w + 1e-16f);

    float4 ac = make_float4(0.f, 0.f, 0.f, 0.f);

    for (int cb = 0; cb < cnt; cb += 64) {
        int ccnt = min(64, cnt - cb);
        int e = 0, s = 0;
        float4 p0 = make_float4(0.f, 0.f, 0.f, 0.f), p1 = p0;
        if (lane < ccnt) {
            e = sortedE[s0 + cb + lane];
            s = sortedS[s0 + cb + lane];
            p0 = *reinterpret_cast<const float4*>(scoreH + (size_t)e * 8);
            p1 = *reinterpret_cast<const float4*>(scoreH + (size_t)e * 8 + 4);
        }
        eL[w][lane] = e;
        sL[w][lane] = s;
        aL[w][lane * 8 + 0] = p0.x * inv[0]; aL[w][lane * 8 + 1] = p0.y * inv[1];
        aL[w][lane * 8 + 2] = p0.z * inv[2]; aL[w][lane * 8 + 3] = p0.w * inv[3];
        aL[w][lane * 8 + 4] = p1.x * inv[4]; aL[w][lane * 8 + 5] = p1.y * inv[5];
        aL[w][lane * 8 + 6] = p1.z * inv[6]; aL[w][lane * 8 + 7] = p1.w * inv[7];
        asm volatile("s_waitcnt lgkmcnt(0)" ::: "memory");
        __builtin_amdgcn_sched_barrier(0);
        int np = (ccnt + 1) >> 1;
#pragma unroll 2
        for (int i = 0; i < np; i++) {
            int ii = i * 2 + half;                 // padded slots staged as zeros
            int e2 = eL[w][ii], s2 = sL[w][ii];
            float al = aL[w][ii * 8 + h];
            float4 we = *reinterpret_cast<const float4*>(wE + (size_t)e2 * 128 + col);
            float4 vv = *reinterpret_cast<const float4*>(V + (size_t)s2 * 128 + col);
            ac.x += (vv.x + we.x) * al;
            ac.y += (vv.y + we.y) * al;
            ac.z += (vv.z + we.z) * al;
            ac.w += (vv.w + we.w) * al;
        }
    }
    ac.x += __shfl_xor(ac.x, 32);
    ac.y += __shfl_xor(ac.y, 32);
    ac.z += __shfl_xor(ac.z, 32);
    ac.w += __shfl_xor(ac.w, 32);
    if (half == 0) *reinterpret_cast<float4*>(wV + (size_t)n * 128 + col) = ac;
}

extern "C" void kernel_launch(void* const* d_in, const int* in_sizes, int n_in,
                              void* d_out, int out_size, void* d_ws, size_t ws_size,
                              hipStream_t stream) {
    const float* x    = (const float*)d_in[0];
    const float* ea   = (const float*)d_in[1];
    const int*   eidx = (const int*)d_in[2];
    const float* WQ   = (const float*)d_in[3];
    const float* bQ   = (const float*)d_in[4];
    const float* WK   = (const float*)d_in[5];
    const float* WV   = (const float*)d_in[6];
    const float* WE1  = (const float*)d_in[7];
    const float* bE1  = (const float*)d_in[8];

    float* wV = (float*)d_out;                           // [50000,128]
    float* wE = (float*)d_out + (size_t)NNODES * 128;    // [800000,128]

    float* Q      = (float*)d_ws;
    float* K      = Q + (size_t)NNODES * 128;
    float* V      = K + (size_t)NNODES * 128;
    float* scoreH = V + (size_t)NNODES * 128;            // [800000,8] ex values
    float* denom  = scoreH + (size_t)NEDGES * 8;         // [50000,8]
    unsigned short* Wt = (unsigned short*)(denom + (size_t)NNODES * 8); // 4x[128][128] bf16
    int* histo   = (int*)(Wt + 4 * 16384);               // 50176
    int* start   = histo + 50176;                        // 50177
    int* cursor  = start + 50177;                        // 50176
    int* sortedE = cursor + 50176;                       // 800000
    int* sortedS = sortedE + NEDGES;                     // 800000
    int* bsum    = sortedS + NEDGES;                     // 256
    int* boff    = bsum + 256;                           // 256

    hipMemsetAsync(histo, 0, (size_t)50176 * 4, stream);
    hipMemsetAsync(denom, 0, (size_t)NNODES * 8 * 4, stream);

    prep_weights<<<(4 * 16384 + 255) / 256, 256, 0, stream>>>(WQ, WK, WV, WE1, Wt);
    hist_kernel<<<(NEDGES + 255) / 256, 256, 0, stream>>>(eidx, histo);
    scanA<<<196, 256, 0, stream>>>(histo, bsum);
    scanB<<<1, 256, 0, stream>>>(bsum, boff);
    scanC<<<196, 256, 0, stream>>>(histo, boff, start, cursor);
    scatter_edges<<<(NEDGES + 255) / 256, 256, 0, stream>>>(eidx, cursor, sortedE, sortedS);
    proj_qkv<<<(NNODES + 63) / 64, 256, 0, stream>>>(x, Wt, bQ, Q, K, V);
    edge_score<<<NEDGES / 128, 512, 0, stream>>>(ea, Wt, bE1, eidx, Q, K, wE, scoreH, denom);
    aggregate_pernode<<<(NNODES + 3) / 4, 256, 0, stream>>>(sortedE, sortedS, start, scoreH, denom, V, wE, wV);
}

// Round 10
// 514.426 us; speedup vs baseline: 1.7095x; 1.1124x over previous
//
#include <hip/hip_runtime.h>
#include <hip/hip_bf16.h>

#define NNODES 50000
#define NEDGES 800000
#define NHEAD 8

typedef __attribute__((ext_vector_type(8))) short short8v;
typedef __attribute__((ext_vector_type(4))) float f32x4;

union U8 { short8v v; unsigned short u[8]; };

__device__ inline unsigned short f2bf(float f) {
    unsigned int u = __float_as_uint(f);
    unsigned int r = (u + 0x7FFFu + ((u >> 16) & 1u)) >> 16;
    return (unsigned short)r;
}
__device__ inline float bf2f(unsigned int u) {
    return __uint_as_float(u << 16);
}

// ---- prep: W[k][n] f32 -> Wt[n][k] bf16, for WQ,WK,WV,WE1 ----
__global__ void prep_weights(const float* __restrict__ WQ, const float* __restrict__ WK,
                             const float* __restrict__ WV, const float* __restrict__ WE1,
                             unsigned short* __restrict__ Wt) {
    int idx = blockIdx.x * 256 + threadIdx.x;
    if (idx >= 4 * 16384) return;
    int m = idx >> 14, r = idx & 16383;
    int k = r >> 7, n = r & 127;
    const float* W = (m == 0) ? WQ : (m == 1) ? WK : (m == 2) ? WV : WE1;
    Wt[m * 16384 + n * 128 + k] = f2bf(W[k * 128 + n]);
}

// swizzled LDS byte offset: row-major [rows][128 bf16] (256B rows), 16-slot XOR swizzle
__device__ inline int swz(int row, int byteInRow) {
    return row * 256 + (byteInRow ^ ((row & 15) << 4));
}

// stage one 128x128 bf16 (pre-transposed) weight into swizzled LDS, 256 threads
__device__ inline void stageW256(char* Wl, const unsigned short* __restrict__ Wtm, int t) {
    int row = t >> 1, half = t & 1;
    const unsigned short* src = Wtm + row * 128 + half * 64;
#pragma unroll
    for (int i = 0; i < 8; i++) {
        short8v v = *reinterpret_cast<const short8v*>(src + i * 8);
        *reinterpret_cast<short8v*>(Wl + swz(row, half * 128 + i * 16)) = v;
    }
}

// stage one 128x128 bf16 (pre-transposed) weight into swizzled LDS, 512 threads
__device__ inline void stageW512(char* Wl, const unsigned short* __restrict__ Wtm, int t) {
    int row = t >> 2, q = t & 3;
    const unsigned short* src = Wtm + row * 128 + q * 32;
#pragma unroll
    for (int i = 0; i < 4; i++) {
        short8v v = *reinterpret_cast<const short8v*>(src + i * 8);
        *reinterpret_cast<short8v*>(Wl + swz(row, q * 64 + i * 16)) = v;
    }
}

// load one bf16 fragment set (4 k-steps) for global row `aptr`, lane k-group lg
__device__ inline void loadAfrag(const float* aptr, int lg, short8v* a, bool ok) {
#pragma unroll
    for (int kk = 0; kk < 4; kk++) {
        U8 h;
        if (ok) {
            float4 f0 = *reinterpret_cast<const float4*>(aptr + kk * 32 + lg * 8);
            float4 f1 = *reinterpret_cast<const float4*>(aptr + kk * 32 + lg * 8 + 4);
            h.u[0] = f2bf(f0.x); h.u[1] = f2bf(f0.y); h.u[2] = f2bf(f0.z); h.u[3] = f2bf(f0.w);
            h.u[4] = f2bf(f1.x); h.u[5] = f2bf(f1.y); h.u[6] = f2bf(f1.z); h.u[7] = f2bf(f1.w);
        } else {
#pragma unroll
            for (int j = 0; j < 8; j++) h.u[j] = 0;
        }
        a[kk] = h.v;
    }
}

// ---- proj: Q = x@WQ + bQ ; K = x@WK ; V = x@WV ----
__global__ __launch_bounds__(256, 4) void proj_qkv(const float* __restrict__ x,
                                                   const unsigned short* __restrict__ Wt,
                                                   const float* __restrict__ bQ,
                                                   float* __restrict__ Q, float* __restrict__ K,
                                                   float* __restrict__ V) {
    __shared__ __align__(16) char Wl[32768];
    int t = threadIdx.x;
    int nb = blockIdx.x * 64;
    int lane = t & 63, w = t >> 6;
    int lg = lane >> 4, lr = lane & 15;

    int arow = nb + w * 16 + lr;
    bool ok = arow < NNODES;
    short8v a[4];
    loadAfrag(x + (size_t)arow * 128, lg, a, ok);

    float bq[8];
#pragma unroll
    for (int n = 0; n < 8; n++) bq[n] = bQ[n * 16 + lr];

    for (int m = 0; m < 3; m++) {
        __syncthreads();
        stageW256(Wl, Wt + m * 16384, t);
        __syncthreads();

        f32x4 acc[8];
#pragma unroll
        for (int n = 0; n < 8; n++) acc[n] = (f32x4){0.f, 0.f, 0.f, 0.f};
#pragma unroll
        for (int kk = 0; kk < 4; kk++) {
#pragma unroll
            for (int n = 0; n < 8; n++) {
                short8v b = *reinterpret_cast<short8v*>(Wl + swz(n * 16 + lr, (kk * 32 + lg * 8) * 2));
                acc[n] = __builtin_amdgcn_mfma_f32_16x16x32_bf16(a[kk], b, acc[n], 0, 0, 0);
            }
        }
        float* out = (m == 0) ? Q : (m == 1) ? K : V;
#pragma unroll
        for (int n = 0; n < 8; n++) {
            int c = n * 16 + lr;
            float bias = (m == 0) ? bq[n] : 0.f;
#pragma unroll
            for (int r = 0; r < 4; r++) {
                int gr = nb + w * 16 + lg * 4 + r;
                if (gr < NNODES) out[(size_t)gr * 128 + c] = acc[n][r] + bias;
            }
        }
    }
}

// ---- edge pass: E GEMM -> E-tile in LDS (bf16) -> row-parallel gather epilogue ----
// 512 threads = 8 waves, 128 edges/block. Coalesced wE stores (wave spans one edge row).
// scoreH stores ex=exp(clamp(sum/4)) (|score|<=5 so no segment max needed); denom atomic.
__global__ __launch_bounds__(512, 6) void edge_score(const float* __restrict__ EA,
                                                     const unsigned short* __restrict__ Wt,
                                                     const float* __restrict__ bE1,
                                                     const int* __restrict__ eidx,
                                                     const float* __restrict__ Q,
                                                     const float* __restrict__ K,
                                                     float* __restrict__ wE,
                                                     float* __restrict__ scoreH,
                                                     float* __restrict__ denom) {
    __shared__ __align__(16) char Wl[32768];   // weights, then E tile (128x128 bf16)
    __shared__ int srcL[128], dstL[128];
    int t = threadIdx.x;
    int eb = blockIdx.x * 128;
    int lane = t & 63, w = t >> 6;
    int lg = lane >> 4, lr = lane & 15;

    stageW512(Wl, Wt + 3 * 16384, t);
    if (t < 128) srcL[t] = eidx[eb + t];
    else if (t < 256) dstL[t - 128] = eidx[NEDGES + eb + t - 128];
    float be[8];
#pragma unroll
    for (int n = 0; n < 8; n++) be[n] = bE1[n * 16 + lr];

    int arow = eb + w * 16 + lr;  // always < NEDGES (grid exact)
    short8v a[4];
    loadAfrag(EA + (size_t)arow * 128, lg, a, true);

    __syncthreads();

    f32x4 acc[8];
#pragma unroll
    for (int n = 0; n < 8; n++) acc[n] = (f32x4){0.f, 0.f, 0.f, 0.f};
#pragma unroll
    for (int kk = 0; kk < 4; kk++) {
#pragma unroll
        for (int n = 0; n < 8; n++) {
            short8v b = *reinterpret_cast<short8v*>(Wl + swz(n * 16 + lr, (kk * 32 + lg * 8) * 2));
            acc[n] = __builtin_amdgcn_mfma_f32_16x16x32_bf16(a[kk], b, acc[n], 0, 0, 0);
        }
    }

    __syncthreads();  // all waves done reading the weight tile

    // write E = acc + bias to LDS as bf16; wave w owns rows [w*16, w*16+16)
#pragma unroll
    for (int n = 0; n < 8; n++) {
#pragma unroll
        for (int r = 0; r < 4; r++) {
            int row = w * 16 + lg * 4 + r;
            *reinterpret_cast<unsigned short*>(Wl + swz(row, (n * 16 + lr) * 2)) =
                f2bf(acc[n][r] + be[n]);
        }
    }
    // no barrier: each wave reads back only its own rows

    // gather epilogue: 64 lanes span one edge row (2 cols/lane)
    int h = lane >> 3;  // head of this lane's columns
#pragma unroll 4
    for (int i = 0; i < 16; i++) {
        int loc = w * 16 + i;
        int e = eb + loc;
        int s = srcL[loc], d = dstL[loc];
        unsigned int ep = *reinterpret_cast<unsigned int*>(Wl + swz(loc, lane * 4));
        float e0 = bf2f(ep & 0xffffu);
        float e1 = bf2f(ep >> 16);
        float2 kv = *reinterpret_cast<const float2*>(K + (size_t)s * 128 + lane * 2);
        float2 qv = *reinterpret_cast<const float2*>(Q + (size_t)d * 128 + lane * 2);
        float s0 = e0 * kv.x * qv.x;
        float s1 = e1 * kv.y * qv.y;
        *reinterpret_cast<float2*>(wE + (size_t)e * 128 + lane * 2) = make_float2(s0, s1);
        float sum = s0 + s1;
        sum += __shfl_xor(sum, 1);
        sum += __shfl_xor(sum, 2);
        sum += __shfl_xor(sum, 4);
        if ((lane & 7) == 0) {
            float sh = fminf(fmaxf(sum * 0.25f, -5.f), 5.f);
            float ex = __expf(sh);
            scoreH[(size_t)e * 8 + h] = ex;
            unsafeAtomicAdd(&denom[d * 8 + h], ex);
        }
    }
}

// ---- counting sort by dst ----
__global__ void hist_kernel(const int* __restrict__ eidx, int* __restrict__ histo) {
    int e = blockIdx.x * 256 + threadIdx.x;
    if (e >= NEDGES) return;
    atomicAdd(&histo[eidx[NEDGES + e]], 1);
}

__global__ __launch_bounds__(256) void scanA(const int* __restrict__ histo, int* __restrict__ bsum) {
    __shared__ int l[4];
    int t = threadIdx.x;
    int idx = blockIdx.x * 256 + t;
    int v = (idx < NNODES) ? histo[idx] : 0;
#pragma unroll
    for (int off = 32; off; off >>= 1) v += __shfl_down(v, off);
    if ((t & 63) == 0) l[t >> 6] = v;
    __syncthreads();
    if (t == 0) bsum[blockIdx.x] = l[0] + l[1] + l[2] + l[3];
}

__global__ __launch_bounds__(256) void scanB(const int* __restrict__ bsum, int* __restrict__ boff) {
    __shared__ int l[256];
    int t = threadIdx.x;
    int v = (t < 196) ? bsum[t] : 0;
    l[t] = v;
    __syncthreads();
    for (int off = 1; off < 256; off <<= 1) {
        int tmp = (t >= off) ? l[t - off] : 0;
        __syncthreads();
        l[t] += tmp;
        __syncthreads();
    }
    if (t < 196) boff[t] = l[t] - v;
}

__global__ __launch_bounds__(256) void scanC(const int* __restrict__ histo,
                                             const int* __restrict__ boff,
                                             int* __restrict__ start, int* __restrict__ cursor) {
    __shared__ int l[256];
    int t = threadIdx.x;
    int idx = blockIdx.x * 256 + t;
    int v = (idx < NNODES) ? histo[idx] : 0;
    l[t] = v;
    __syncthreads();
    for (int off = 1; off < 256; off <<= 1) {
        int tmp = (t >= off) ? l[t - off] : 0;
        __syncthreads();
        l[t] += tmp;
        __syncthreads();
    }
    int excl = l[t] - v + boff[blockIdx.x];
    if (idx <= NNODES) {
        start[idx] = excl;
        if (idx < NNODES) cursor[idx] = excl;
    }
}

// scatter edges sorted by dst; also emit src per sorted slot (kills eidx gather later)
__global__ void scatter_edges(const int* __restrict__ eidx, int* __restrict__ cursor,
                              int* __restrict__ sortedE, int* __restrict__ sortedS) {
    int e = blockIdx.x * 256 + threadIdx.x;
    if (e >= NEDGES) return;
    int d = eidx[NEDGES + e];
    int s = eidx[e];
    int pos = atomicAdd(&cursor[d], 1);
    sortedE[pos] = e;
    sortedS[pos] = s;
}

// ---- aggregation: one wave per dst node; alpha = ex * 1/denom; single pass ----
// 2 edges per iteration: half-waves cover edges 2i / 2i+1, float4 columns.
__global__ __launch_bounds__(256, 8) void aggregate_pernode(const int* __restrict__ sortedE,
                                                            const int* __restrict__ sortedS,
                                                            const int* __restrict__ start,
                                                            const float* __restrict__ scoreH,
                                                            const float* __restrict__ denom,
                                                            const float* __restrict__ V,
                                                            const float* __restrict__ wE,
                                                            float* __restrict__ wV) {
    __shared__ int eL[4][64];
    __shared__ int sL[4][64];
    __shared__ float aL[4][512];
    int w = threadIdx.x >> 6;
    int n = blockIdx.x * 4 + w;
    if (n >= NNODES) return;
    int lane = threadIdx.x & 63;
    int half = lane >> 5, li = lane & 31;
    int col = li * 4, h = li >> 2;
    int s0 = start[n], cnt = start[n + 1] - s0;

    float4 d0 = *reinterpret_cast<const float4*>(denom + n * 8);
    float4 d1 = *reinterpret_cast<const float4*>(denom + n * 8 + 4);
    float inv[8];
    inv[0] = 1.f / (d0.x + 1e-16f); inv[1] = 1.f / (d0.y + 1e-16f);
    inv[2] = 1.f / (d0.z + 1e-16f); inv[3] = 1.f / (d0.w + 1e-16f);
    inv[4] = 1.f / (d1.x + 1e-16f); inv[5] = 1.f / (d1.y + 1e-16f);
    inv[6] = 1.f / (d1.z + 1e-16f); inv[7] = 1.f / (d1.w + 1e-16f);

    float4 ac = make_float4(0.f, 0.f, 0.f, 0.f);

    for (int cb = 0; cb < cnt; cb += 64) {
        int ccnt = min(64, cnt - cb);
        int e = 0, s = 0;
        float4 p0 = make_float4(0.f, 0.f, 0.f, 0.f), p1 = p0;
        if (lane < ccnt) {
            e = sortedE[s0 + cb + lane];
            s = sortedS[s0 + cb + lane];
            p0 = *reinterpret_cast<const float4*>(scoreH + (size_t)e * 8);
            p1 = *reinterpret_cast<const float4*>(scoreH + (size_t)e * 8 + 4);
        }
        eL[w][lane] = e;
        sL[w][lane] = s;
        aL[w][lane * 8 + 0] = p0.x * inv[0]; aL[w][lane * 8 + 1] = p0.y * inv[1];
        aL[w][lane * 8 + 2] = p0.z * inv[2]; aL[w][lane * 8 + 3] = p0.w * inv[3];
        aL[w][lane * 8 + 4] = p1.x * inv[4]; aL[w][lane * 8 + 5] = p1.y * inv[5];
        aL[w][lane * 8 + 6] = p1.z * inv[6]; aL[w][lane * 8 + 7] = p1.w * inv[7];
        asm volatile("s_waitcnt lgkmcnt(0)" ::: "memory");
        __builtin_amdgcn_sched_barrier(0);
        int np = (ccnt + 1) >> 1;
#pragma unroll 2
        for (int i = 0; i < np; i++) {
            int ii = i * 2 + half;                 // padded slots staged as zeros
            int e2 = eL[w][ii], s2 = sL[w][ii];
            float al = aL[w][ii * 8 + h];
            float4 we = *reinterpret_cast<const float4*>(wE + (size_t)e2 * 128 + col);
            float4 vv = *reinterpret_cast<const float4*>(V + (size_t)s2 * 128 + col);
            ac.x += (vv.x + we.x) * al;
            ac.y += (vv.y + we.y) * al;
            ac.z += (vv.z + we.z) * al;
            ac.w += (vv.w + we.w) * al;
        }
    }
    ac.x += __shfl_xor(ac.x, 32);
    ac.y += __shfl_xor(ac.y, 32);
    ac.z += __shfl_xor(ac.z, 32);
    ac.w += __shfl_xor(ac.w, 32);
    if (half == 0) *reinterpret_cast<float4*>(wV + (size_t)n * 128 + col) = ac;
}

extern "C" void kernel_launch(void* const* d_in, const int* in_sizes, int n_in,
                              void* d_out, int out_size, void* d_ws, size_t ws_size,
                              hipStream_t stream) {
    const float* x    = (const float*)d_in[0];
    const float* ea   = (const float*)d_in[1];
    const int*   eidx = (const int*)d_in[2];
    const float* WQ   = (const float*)d_in[3];
    const float* bQ   = (const float*)d_in[4];
    const float* WK   = (const float*)d_in[5];
    const float* WV   = (const float*)d_in[6];
    const float* WE1  = (const float*)d_in[7];
    const float* bE1  = (const float*)d_in[8];

    float* wV = (float*)d_out;                           // [50000,128]
    float* wE = (float*)d_out + (size_t)NNODES * 128;    // [800000,128]

    float* Q      = (float*)d_ws;
    float* K      = Q + (size_t)NNODES * 128;
    float* V      = K + (size_t)NNODES * 128;
    float* scoreH = V + (size_t)NNODES * 128;            // [800000,8] ex values
    float* denom  = scoreH + (size_t)NEDGES * 8;         // [50000,8]
    unsigned short* Wt = (unsigned short*)(denom + (size_t)NNODES * 8); // 4x[128][128] bf16
    int* histo   = (int*)(Wt + 4 * 16384);               // 50176
    int* start   = histo + 50176;                        // 50177
    int* cursor  = start + 50177;                        // 50176
    int* sortedE = cursor + 50176;                       // 800000
    int* sortedS = sortedE + NEDGES;                     // 800000
    int* bsum    = sortedS + NEDGES;                     // 256
    int* boff    = bsum + 256;                           // 256

    hipMemsetAsync(histo, 0, (size_t)50176 * 4, stream);
    hipMemsetAsync(denom, 0, (size_t)NNODES * 8 * 4, stream);

    prep_weights<<<(4 * 16384 + 255) / 256, 256, 0, stream>>>(WQ, WK, WV, WE1, Wt);
    hist_kernel<<<(NEDGES + 255) / 256, 256, 0, stream>>>(eidx, histo);
    scanA<<<196, 256, 0, stream>>>(histo, bsum);
    scanB<<<1, 256, 0, stream>>>(bsum, boff);
    scanC<<<196, 256, 0, stream>>>(histo, boff, start, cursor);
    scatter_edges<<<(NEDGES + 255) / 256, 256, 0, stream>>>(eidx, cursor, sortedE, sortedS);
    proj_qkv<<<(NNODES + 63) / 64, 256, 0, stream>>>(x, Wt, bQ, Q, K, V);
    edge_score<<<NEDGES / 128, 512, 0, stream>>>(ea, Wt, bE1, eidx, Q, K, wE, scoreH, denom);
    aggregate_pernode<<<(NNODES + 3) / 4, 256, 0, stream>>>(sortedE, sortedS, start, scoreH, denom, V, wE, wV);
}